// Round 5
// baseline (1816.550 us; speedup 1.0000x reference)
//
#include <hip/hip_runtime.h>
#include <hip/hip_bf16.h>

typedef __hip_bfloat16 bf16;
typedef float v4f __attribute__((ext_vector_type(4)));
typedef __attribute__((ext_vector_type(8))) short short8;

__device__ __forceinline__ float b2f(bf16 v) { return __bfloat162float(v); }
__device__ __forceinline__ bf16 f2b(float v) { return __float2bfloat16(v); }

// async global->LDS, 16B per lane. LDS dest = wave-uniform base + lane*16.
__device__ __forceinline__ void gload_lds16(const bf16* g, bf16* l) {
    __builtin_amdgcn_global_load_lds((__attribute__((address_space(1))) void*)(void*)g,
                                     (__attribute__((address_space(3))) void*)l, 16, 0, 0);
}

// Problem constants
#define BB 32
#define CD 384
#define HH 56
#define ND 3136        // 56*56
#define HID 1536
#define GG 7
#define SS 8
#define MROWS 100352   // BB*ND

// window-row (w*64+t) -> token-row (b*ND + n)
__device__ __forceinline__ int wrow_to_token(int orow) {
    int w = orow >> 6, t = orow & 63;
    int bb = w / 49, wr = w % 49;
    int gy = wr / GG, gx = wr % GG;
    int sy = t >> 3, sx = t & 7;
    return bb * ND + (sy * GG + gy) * HH + (sx * GG + gx);
}

// ---------- batched transpose fp32 -> bf16: in[b][r][c] (f32) -> out[b][c][r] (bf16) ----------
__global__ __launch_bounds__(256) void transpose_f2b_k(const float* __restrict__ in,
                                                       bf16* __restrict__ out, int R, int Cc)
{
    __shared__ float tile[32][33];
    int c0 = blockIdx.x * 32, r0 = blockIdx.y * 32;
    size_t bb = blockIdx.z;
    int tx = threadIdx.x & 31, ty = threadIdx.x >> 5;
    const float* ip = in + bb * (size_t)R * Cc;
    bf16* op = out + bb * (size_t)R * Cc;
#pragma unroll
    for (int i = 0; i < 4; i++)
        tile[ty + i * 8][tx] = ip[(size_t)(r0 + ty + i * 8) * Cc + (c0 + tx)];
    __syncthreads();
#pragma unroll
    for (int i = 0; i < 4; i++)
        op[(size_t)(c0 + ty + i * 8) * R + (r0 + tx)] = f2b(tile[tx][ty + i * 8]);
}

// ---------- LayerNorm over C=384, one wave per output row; chunked ----------
__global__ __launch_bounds__(256) void ln_k(const bf16* __restrict__ in,
                                            const float* __restrict__ g,
                                            const float* __restrict__ b,
                                            bf16* __restrict__ out,
                                            int row0, int gather)
{
    int wave = threadIdx.x >> 6, lane = threadIdx.x & 63;
    int row = row0 + blockIdx.x * 4 + wave;
    int src = gather ? wrow_to_token(row) : row;
    const bf16* ip = in + (size_t)src * CD;
    float vals[6];
    float s = 0.f, s2 = 0.f;
#pragma unroll
    for (int i = 0; i < 6; i++) {
        float v = b2f(ip[lane + i * 64]);
        vals[i] = v; s += v; s2 += v * v;
    }
#pragma unroll
    for (int off = 32; off >= 1; off >>= 1) {
        s  += __shfl_xor(s, off);
        s2 += __shfl_xor(s2, off);
    }
    float mean = s * (1.f / CD);
    float var = s2 * (1.f / CD) - mean * mean;
    float rstd = rsqrtf(var + 1e-5f);
    bf16* op = out + (size_t)(row - row0) * CD;
#pragma unroll
    for (int i = 0; i < 6; i++) {
        int c = lane + i * 64;
        op[c] = f2b((vals[i] - mean) * rstd * g[c] + b[c]);
    }
}

// ---------- GEMM: C[M,N] = A[M,K] @ Bt[N,K]^T (+fp32 bias per col), bf16 in, fp32 acc ----------
// m97 structure + T3 "minimum 2-phase": double-buffered LDS, prefetch next K-tile
// before computing current, counted s_waitcnt vmcnt(4) instead of full drain.
// 1-D grid + bijective chunked XCD swizzle (m204).
// If g1 != nullptr: fused resid1 epilogue -> writes x1[token] = xt[token] + g1*(acc+bias),
// with token = wrow_to_token(row0 + global_row); Cm is then the x1 base (token-major).
__global__ __launch_bounds__(256) void gemm_bt(const bf16* __restrict__ A,
                                               const bf16* __restrict__ Bt,
                                               const float* __restrict__ bias,
                                               bf16* __restrict__ Cm,
                                               int M, int N, int K, int gx,
                                               const bf16* __restrict__ xt,
                                               const float* __restrict__ g1,
                                               int row0)
{
    __shared__ __align__(16) bf16 As[2][128][32];
    __shared__ __align__(16) bf16 Bs[2][128][32];
    const int nwg = gridDim.x;
    const int q = nwg >> 3, r = nwg & 7;
    const int xcd = blockIdx.x & 7, id8 = blockIdx.x >> 3;
    const int wgid = (xcd < r ? xcd * (q + 1) : r * (q + 1) + (xcd - r) * q) + id8;
    const int m0 = (wgid / gx) * 128, n0 = (wgid % gx) * 128;

    const int tid = threadIdx.x;
    const int lane = tid & 63, wave = tid >> 6;
    const int rb = (wave >> 1) * 64, cb = (wave & 1) * 64;
    const int lr = lane & 15, ko = (lane >> 4) * 8;
    const int r0s = wave * 32;           // this wave's 32-row staging slab
    const int srow = lane >> 2;          // 0..15 (row within 16-row half-slab)
    const int scol = (lane & 3) * 8;     // element offset (0,8,16,24)

    auto STAGE = [&](int bi, int kk0) {
#pragma unroll
        for (int h = 0; h < 2; h++) {
            int row = r0s + h * 16 + srow;
            gload_lds16(&A [(size_t)(m0 + row) * K + kk0 + scol], &As[bi][r0s + h * 16][0]);
            gload_lds16(&Bt[(size_t)(n0 + row) * K + kk0 + scol], &Bs[bi][r0s + h * 16][0]);
        }
    };

    v4f acc[4][4];
#pragma unroll
    for (int i = 0; i < 4; i++)
#pragma unroll
        for (int j = 0; j < 4; j++) acc[i][j] = (v4f)0.f;

    const int nt = K >> 5;
    int cur = 0;
    STAGE(0, 0);                         // prologue: 4 gload_lds/wave in flight

    for (int t = 0; t < nt; t++) {
        if (t + 1 < nt) {
            STAGE(cur ^ 1, (t + 1) << 5);                    // 8 in flight
            asm volatile("s_waitcnt vmcnt(4)" ::: "memory"); // wait current tile only
        } else {
            asm volatile("s_waitcnt vmcnt(0)" ::: "memory");
        }
        __builtin_amdgcn_s_barrier();        // all waves' current-tile LDS writes done
        __builtin_amdgcn_sched_barrier(0);

        short8 af[4], bfr[4];
#pragma unroll
        for (int mi = 0; mi < 4; mi++) af[mi]  = *(const short8*)&As[cur][rb + mi * 16 + lr][ko];
#pragma unroll
        for (int ni = 0; ni < 4; ni++) bfr[ni] = *(const short8*)&Bs[cur][cb + ni * 16 + lr][ko];
#pragma unroll
        for (int mi = 0; mi < 4; mi++)
#pragma unroll
            for (int ni = 0; ni < 4; ni++)
                acc[mi][ni] = __builtin_amdgcn_mfma_f32_16x16x32_bf16(af[mi], bfr[ni], acc[mi][ni], 0, 0, 0);

        asm volatile("s_waitcnt lgkmcnt(0)" ::: "memory");   // ds_reads complete
        __builtin_amdgcn_sched_barrier(0);
        __builtin_amdgcn_s_barrier();        // safe to overwrite buf[cur] next iter
        cur ^= 1;
    }

#pragma unroll
    for (int ni = 0; ni < 4; ni++) {
        int col = n0 + cb + ni * 16 + lr;
        float bv = bias ? bias[col] : 0.f;
#pragma unroll
        for (int mi = 0; mi < 4; mi++) {
            int rowb = m0 + rb + mi * 16 + (lane >> 4) * 4;
            if (g1 == nullptr) {
#pragma unroll
                for (int r2 = 0; r2 < 4; r2++)
                    Cm[(size_t)(rowb + r2) * N + col] = f2b(acc[mi][ni][r2] + bv);
            } else {
                float gv = g1[col];
#pragma unroll
                for (int r2 = 0; r2 < 4; r2++) {
                    int token = wrow_to_token(row0 + rowb + r2);
                    size_t xi = (size_t)token * CD + col;
                    Cm[xi] = f2b(b2f(xt[xi]) + gv * (acc[mi][ni][r2] + bv));
                }
            }
        }
    }
}

// ---------- MFMA attention: one wave per (window, head); n=64, hd=48 ----------
// Q/K fragments read DIRECT from global (window qkv is L2-resident; zero LDS reuse).
// LDS: P[64] rows x 128B XOR-swizzled (8KB) + V[64][48] (6KB) = 14336B -> 11 blocks/CU.
__global__ __launch_bounds__(64) void attn_mfma_k(const bf16* __restrict__ qkv,
                                                  bf16* __restrict__ o)
{
    __shared__ __align__(16) char lds[14336];
    char* Ps = lds;                    // stride 128 B, swizzled
    bf16* Vs = (bf16*)(lds + 8192);    // stride 48 elems (96 B)

    const int lane = threadIdx.x;
    const int lr = lane & 15, grp = lane >> 4;
    const int lw = blockIdx.x >> 3, head = blockIdx.x & 7;

    const bf16* base = qkv + (size_t)lw * 64 * 1152 + head * 48;

    // ---- stage V only ----
#pragma unroll
    for (int it = 0; it < 6; it++) {
        int i = it * 64 + lane;
        int t = i / 6, s = i - t * 6;
        *(uint4*)((char*)Vs + t * 96 + s * 16) =
            *(const uint4*)(base + (size_t)t * 1152 + 768 + s * 8);
    }

    // ---- S = Q K^T : 4x4 tiles of 16x16; fragments direct from global ----
    v4f accs[4][4];
#pragma unroll
    for (int mi = 0; mi < 4; mi++)
#pragma unroll
        for (int ni = 0; ni < 4; ni++) accs[mi][ni] = (v4f)0.f;

    const short8 z8 = (short8)0;
    {
        short8 qf[4], kf[4];
        // k-step 0: k = grp*8 (0..31)
#pragma unroll
        for (int mi = 0; mi < 4; mi++)
            qf[mi] = *(const short8*)(base + (size_t)(mi * 16 + lr) * 1152 + grp * 8);
#pragma unroll
        for (int ni = 0; ni < 4; ni++)
            kf[ni] = *(const short8*)(base + 384 + (size_t)(ni * 16 + lr) * 1152 + grp * 8);
#pragma unroll
        for (int mi = 0; mi < 4; mi++)
#pragma unroll
            for (int ni = 0; ni < 4; ni++)
                accs[mi][ni] = __builtin_amdgcn_mfma_f32_16x16x32_bf16(qf[mi], kf[ni], accs[mi][ni], 0, 0, 0);
        // k-step 1: k = 32 + grp*8; grp>=2 would be k>=48 -> zero fragment (no pad in global)
#pragma unroll
        for (int mi = 0; mi < 4; mi++)
            qf[mi] = (grp < 2) ? *(const short8*)(base + (size_t)(mi * 16 + lr) * 1152 + 32 + grp * 8) : z8;
#pragma unroll
        for (int ni = 0; ni < 4; ni++)
            kf[ni] = (grp < 2) ? *(const short8*)(base + 384 + (size_t)(ni * 16 + lr) * 1152 + 32 + grp * 8) : z8;
#pragma unroll
        for (int mi = 0; mi < 4; mi++)
#pragma unroll
            for (int ni = 0; ni < 4; ni++)
                accs[mi][ni] = __builtin_amdgcn_mfma_f32_16x16x32_bf16(qf[mi], kf[ni], accs[mi][ni], 0, 0, 0);
    }

    // ---- wave-parallel softmax over cols ----
    const float scale = 0.14433756729740643f; // 48^-0.5
#pragma unroll
    for (int mi = 0; mi < 4; mi++)
#pragma unroll
        for (int ni = 0; ni < 4; ni++) accs[mi][ni] *= scale;

    float inv_s[4][4];
#pragma unroll
    for (int mi = 0; mi < 4; mi++) {
#pragma unroll
        for (int r = 0; r < 4; r++) {
            float mx = fmaxf(fmaxf(accs[mi][0][r], accs[mi][1][r]),
                             fmaxf(accs[mi][2][r], accs[mi][3][r]));
#pragma unroll
            for (int off = 8; off >= 1; off >>= 1) mx = fmaxf(mx, __shfl_xor(mx, off));
            float sum = 0.f;
#pragma unroll
            for (int ni = 0; ni < 4; ni++) {
                float e = __expf(accs[mi][ni][r] - mx);
                accs[mi][ni][r] = e;
                sum += e;
            }
#pragma unroll
            for (int off = 8; off >= 1; off >>= 1) sum += __shfl_xor(sum, off);
            inv_s[mi][r] = 1.f / sum;
        }
    }

    // ---- write unnormalized P (bf16) to swizzled LDS ----
#pragma unroll
    for (int mi = 0; mi < 4; mi++)
#pragma unroll
        for (int ni = 0; ni < 4; ni++)
#pragma unroll
            for (int r = 0; r < 4; r++) {
                int i = mi * 16 + grp * 4 + r;
                int j = ni * 16 + lr;
                int byte = (i * 128 + j * 2) ^ ((i & 7) << 4);
                *(bf16*)(Ps + byte) = f2b(accs[mi][ni][r]);
            }

    // ---- O = P V : M=64, N=48, K=64 -> 4x3 tiles, 2 k-steps ----
    v4f acco[4][3];
#pragma unroll
    for (int mi = 0; mi < 4; mi++)
#pragma unroll
        for (int ni = 0; ni < 3; ni++) acco[mi][ni] = (v4f)0.f;

    const short* vsp = (const short*)Vs;
#pragma unroll
    for (int kk = 0; kk < 2; kk++) {
        int k0 = kk * 32 + grp * 8;
        short8 pf[4];
#pragma unroll
        for (int mi = 0; mi < 4; mi++) {
            int row = mi * 16 + lr;
            int byte = (row * 128 + k0 * 2) ^ ((row & 7) << 4);
            pf[mi] = *(const short8*)(Ps + byte);
        }
        short8 vf[3];
#pragma unroll
        for (int ni = 0; ni < 3; ni++) {
#pragma unroll
            for (int jj = 0; jj < 8; jj++)
                vf[ni][jj] = vsp[(k0 + jj) * 48 + ni * 16 + lr];
        }
#pragma unroll
        for (int mi = 0; mi < 4; mi++)
#pragma unroll
            for (int ni = 0; ni < 3; ni++)
                acco[mi][ni] = __builtin_amdgcn_mfma_f32_16x16x32_bf16(pf[mi], vf[ni], acco[mi][ni], 0, 0, 0);
    }

    // ---- epilogue: scale by 1/rowsum, store ----
    bf16* op = o + (size_t)lw * 64 * CD + head * 48;
#pragma unroll
    for (int mi = 0; mi < 4; mi++)
#pragma unroll
        for (int r = 0; r < 4; r++) {
            int t = mi * 16 + grp * 4 + r;
            float is = inv_s[mi][r];
#pragma unroll
            for (int ni = 0; ni < 3; ni++)
                op[(size_t)t * CD + ni * 16 + lr] = f2b(acco[mi][ni][r] * is);
        }
}

// ---------- depthwise 3x3 conv + bias + exact GELU: register sliding window ----------
__global__ __launch_bounds__(256) void dwconv_gelu_k(const bf16* __restrict__ m1c,
                                                     const float* __restrict__ wgt,
                                                     const float* __restrict__ bias,
                                                     bf16* __restrict__ gc)
{
    const int c  = blockIdx.x * 64 + (threadIdx.x & 63);
    const int xq = threadIdx.x >> 6;
    const int xx = blockIdx.y * 8 + xq * 2;     // first of 2 x positions (<= 54)
    const int lb = blockIdx.z >> 2;
    const int ys = (blockIdx.z & 3) * 14;

    float w9[9];
#pragma unroll
    for (int i = 0; i < 9; i++) w9[i] = wgt[c * 9 + i];
    const float bs = bias[c];

    const bf16* base = m1c + (size_t)lb * ND * HID + c;
    bool  v[4];
    const bf16* colp[4];
#pragma unroll
    for (int i = 0; i < 4; i++) {
        int xc = xx - 1 + i;
        v[i] = (xc >= 0 && xc < HH);
        int xcl = xc < 0 ? 0 : (xc > HH - 1 ? HH - 1 : xc);
        colp[i] = base + (size_t)xcl * HID;
    }
    const size_t ystride = (size_t)HH * HID;

    float win[3][4];
    {
        int ym = ys - 1;
        int ymc = ym < 0 ? 0 : ym;
        bool yv = (ym >= 0);
#pragma unroll
        for (int i = 0; i < 4; i++)
            win[0][i] = (yv && v[i]) ? b2f(colp[i][(size_t)ymc * ystride]) : 0.f;
#pragma unroll
        for (int i = 0; i < 4; i++)
            win[1][i] = v[i] ? b2f(colp[i][(size_t)ys * ystride]) : 0.f;
    }

#pragma unroll
    for (int s = 0; s < 14; s++) {
        const int y = ys + s;
        const int yp = y + 1;
        const bool yv = (yp < HH);
        const int ypc = yv ? yp : (HH - 1);
#pragma unroll
        for (int i = 0; i < 4; i++)
            win[2][i] = (yv && v[i]) ? b2f(colp[i][(size_t)ypc * ystride]) : 0.f;

        float a0 = bs, a1 = bs;
#pragma unroll
        for (int r = 0; r < 3; r++)
#pragma unroll
            for (int j = 0; j < 3; j++) {
                a0 = fmaf(w9[r * 3 + j], win[r][j],     a0);
                a1 = fmaf(w9[r * 3 + j], win[r][j + 1], a1);
            }
        float g0 = 0.5f * a0 * (1.f + erff(a0 * 0.70710678118654752f));
        float g1 = 0.5f * a1 * (1.f + erff(a1 * 0.70710678118654752f));
        size_t o0 = ((size_t)lb * ND + (size_t)y * HH + xx) * HID + c;
        gc[o0]       = f2b(g0);
        gc[o0 + HID] = f2b(g1);

#pragma unroll
        for (int i = 0; i < 4; i++) { win[0][i] = win[1][i]; win[1][i] = win[2][i]; }
    }
}

// ---------- residual 2 + transpose to NCHW fp32 output (chunk of nb images at b0) ----------
__global__ __launch_bounds__(256) void resid2_k(const bf16* __restrict__ x1,
                                                const bf16* __restrict__ m2c,
                                                const float* __restrict__ gamma2,
                                                float* __restrict__ out, int b0)
{
    __shared__ float tile[32][33];
    int n0 = blockIdx.x * 32, c0 = blockIdx.y * 32;
    int lb = blockIdx.z, gb = b0 + lb;
    int tx = threadIdx.x & 31, ty = threadIdx.x >> 5;
#pragma unroll
    for (int i = 0; i < 4; i++) {
        int n = n0 + ty + i * 8, c = c0 + tx;
        size_t sx1 = ((size_t)gb * ND + n) * CD + c;
        size_t sm  = ((size_t)lb * ND + n) * CD + c;
        tile[ty + i * 8][tx] = b2f(x1[sx1]) + gamma2[c] * b2f(m2c[sm]);
    }
    __syncthreads();
#pragma unroll
    for (int i = 0; i < 4; i++) {
        int c = c0 + ty + i * 8, n = n0 + tx;
        out[((size_t)gb * CD + c) * ND + n] = tile[tx][ty + i * 8];
    }
}

extern "C" void kernel_launch(void* const* d_in, const int* in_sizes, int n_in,
                              void* d_out, int out_size, void* d_ws, size_t ws_size,
                              hipStream_t stream) {
    const float* x      = (const float*)d_in[0];
    const float* ln1_g  = (const float*)d_in[1];
    const float* ln1_b  = (const float*)d_in[2];
    const float* qkv_w  = (const float*)d_in[3];
    const float* proj_w = (const float*)d_in[4];
    const float* proj_b = (const float*)d_in[5];
    const float* ln2_g  = (const float*)d_in[6];
    const float* ln2_b  = (const float*)d_in[7];
    const float* fc1_w  = (const float*)d_in[8];
    const float* fc1_b  = (const float*)d_in[9];
    const float* dw_w   = (const float*)d_in[10];
    const float* dw_b   = (const float*)d_in[11];
    const float* fc2_w  = (const float*)d_in[12];
    const float* fc2_b  = (const float*)d_in[13];
    const float* gamma1 = (const float*)d_in[14];
    const float* gamma2 = (const float*)d_in[15];
    float* out = (float*)d_out;

    const size_t SZ_TOK = (size_t)MROWS * CD * 2;   // bf16 token-major
    const size_t S0 = 2 * SZ_TOK;
    const size_t WTS = 3538944;                     // transposed-weights block

    // MLP chunking: cm=8 if the workspace fits it, else 16
    const size_t attn_end8 = S0 + (size_t)(MROWS / 8) * CD * 2 + (size_t)(MROWS / 8) * 1152 * 2;
    int cm = 16;
    {
        size_t mc2 = (size_t)(BB / 8) * ND;
        size_t mlp_end8 = S0 + mc2 * CD * 2 + 2 * mc2 * HID * 2;
        size_t tot8 = (mlp_end8 > attn_end8 ? mlp_end8 : attn_end8) + WTS;
        if (ws_size >= tot8) cm = 8;
    }
    const int nb = BB / cm;
    const int Mc2 = nb * ND;
    const size_t sz_h2 = (size_t)Mc2 * CD * 2;
    const size_t sz_m1 = (size_t)Mc2 * HID * 2;
    const size_t mlp_end = S0 + sz_h2 + 2 * sz_m1;

    // attention chunking: smallest ca in {2,4,8} that fits
    int ca = 0;
    size_t sz_h = 0, sz_qk = 0, attn_end = 0;
    for (int cand = 2; cand <= 8 && !ca; cand <<= 1) {
        int McA_ = MROWS / cand;
        size_t h_ = (size_t)McA_ * CD * 2, qk_ = (size_t)McA_ * 1152 * 2;
        size_t ae = S0 + h_ + qk_;
        size_t tot = (mlp_end > ae ? mlp_end : ae) + WTS;
        if (ws_size >= tot) { ca = cand; sz_h = h_; sz_qk = qk_; attn_end = ae; }
    }
    if (!ca) return;
    const int McA = MROWS / ca;

    const size_t Wo = (mlp_end > attn_end ? mlp_end : attn_end);

    char* w = (char*)d_ws;
    bf16* xt      = (bf16*)(w + 0);
    bf16* x1      = (bf16*)(w + SZ_TOK);
    bf16* hc      = (bf16*)(w + S0);                // attention: h / o (aliased)
    bf16* qkvc    = (bf16*)(w + S0 + sz_h);         // attention: qkv (aliased)
    bf16* h2c     = (bf16*)(w + S0);                // MLP: h2 / m2 (aliased)
    bf16* m1c     = (bf16*)(w + S0 + sz_h2);
    bf16* gc      = (bf16*)(w + S0 + sz_h2 + sz_m1);
    bf16* qkv_wt  = (bf16*)(w + Wo);
    bf16* proj_wt = (bf16*)(w + Wo + 884736);
    bf16* fc1_wt  = (bf16*)(w + Wo + 884736 + 294912);
    bf16* fc2_wt  = (bf16*)(w + Wo + 884736 + 294912 + 1179648);

    dim3 blk(256);

    // fp32 -> bf16 transposes: x -> xt (token-major), weights -> K-contiguous (B^T)
    transpose_f2b_k<<<dim3(98, 12, 32), blk, 0, stream>>>(x, xt, CD, ND);
    transpose_f2b_k<<<dim3(36, 12, 1), blk, 0, stream>>>(qkv_w, qkv_wt, CD, 1152);
    transpose_f2b_k<<<dim3(12, 12, 1), blk, 0, stream>>>(proj_w, proj_wt, CD, CD);
    transpose_f2b_k<<<dim3(48, 12, 1), blk, 0, stream>>>(fc1_w, fc1_wt, CD, HID);
    transpose_f2b_k<<<dim3(12, 48, 1), blk, 0, stream>>>(fc2_w, fc2_wt, HID, CD);

    // ---- attention phase: ca chunks of McA window rows ----
    for (int ch = 0; ch < ca; ch++) {
        int row0 = ch * McA;
        ln_k<<<McA / 4, blk, 0, stream>>>(xt, ln1_g, ln1_b, hc, row0, 1);
        gemm_bt<<<dim3(9 * (McA / 128)), blk, 0, stream>>>(hc, qkv_wt, nullptr, qkvc,
                                                           McA, 1152, CD, 9, nullptr, nullptr, 0);
        attn_mfma_k<<<(McA / 64) * 8, dim3(64), 0, stream>>>(qkvc, hc);   // o -> hc
        // proj GEMM with fused resid1: writes x1[token] = xt[token] + gamma1*(o@W + b)
        gemm_bt<<<dim3(3 * (McA / 128)), blk, 0, stream>>>(hc, proj_wt, proj_b, x1,
                                                           McA, CD, CD, 3, xt, gamma1, row0);
    }

    // ---- MLP phase: cm chunks of nb whole images ----
    for (int ch = 0; ch < cm; ch++) {
        int r0 = ch * Mc2, b0 = ch * nb;
        ln_k<<<Mc2 / 4, blk, 0, stream>>>(x1, ln2_g, ln2_b, h2c, r0, 0);
        gemm_bt<<<dim3(12 * (Mc2 / 128)), blk, 0, stream>>>(h2c, fc1_wt, fc1_b, m1c,
                                                            Mc2, HID, CD, 12, nullptr, nullptr, 0);
        dwconv_gelu_k<<<dim3(HID / 64, 7, nb * 4), blk, 0, stream>>>(m1c, dw_w, dw_b, gc);
        gemm_bt<<<dim3(3 * (Mc2 / 128)), blk, 0, stream>>>(gc, fc2_wt, fc2_b, h2c,
                                                           Mc2, CD, HID, 3, nullptr, nullptr, 0);
        resid2_k<<<dim3(98, 12, nb), blk, 0, stream>>>(x1, h2c, gamma2, out, b0);
    }
}

// Round 7
// 1697.368 us; speedup vs baseline: 1.0702x; 1.0702x over previous
//
#include <hip/hip_runtime.h>
#include <hip/hip_bf16.h>

typedef __hip_bfloat16 bf16;
typedef float v4f __attribute__((ext_vector_type(4)));
typedef __attribute__((ext_vector_type(8))) short short8;

__device__ __forceinline__ float b2f(bf16 v) { return __bfloat162float(v); }
__device__ __forceinline__ bf16 f2b(float v) { return __float2bfloat16(v); }

// async global->LDS, 16B per lane. LDS dest = wave-uniform base + lane*16.
__device__ __forceinline__ void gload_lds16(const bf16* g, bf16* l) {
    __builtin_amdgcn_global_load_lds((__attribute__((address_space(1))) void*)(void*)g,
                                     (__attribute__((address_space(3))) void*)l, 16, 0, 0);
}

// Problem constants
#define BB 32
#define CD 384
#define HH 56
#define ND 3136        // 56*56
#define HID 1536
#define GG 7
#define SS 8
#define MROWS 100352   // BB*ND

// window-row (w*64+t) -> token-row (b*ND + n)
__device__ __forceinline__ int wrow_to_token(int orow) {
    int w = orow >> 6, t = orow & 63;
    int bb = w / 49, wr = w % 49;
    int gy = wr / GG, gx = wr % GG;
    int sy = t >> 3, sx = t & 7;
    return bb * ND + (sy * GG + gy) * HH + (sx * GG + gx);
}

// ---------- batched transpose fp32 -> bf16: in[b][r][c] (f32) -> out[b][c][r] (bf16) ----------
__global__ __launch_bounds__(256) void transpose_f2b_k(const float* __restrict__ in,
                                                       bf16* __restrict__ out, int R, int Cc)
{
    __shared__ float tile[32][33];
    int c0 = blockIdx.x * 32, r0 = blockIdx.y * 32;
    size_t bb = blockIdx.z;
    int tx = threadIdx.x & 31, ty = threadIdx.x >> 5;
    const float* ip = in + bb * (size_t)R * Cc;
    bf16* op = out + bb * (size_t)R * Cc;
#pragma unroll
    for (int i = 0; i < 4; i++)
        tile[ty + i * 8][tx] = ip[(size_t)(r0 + ty + i * 8) * Cc + (c0 + tx)];
    __syncthreads();
#pragma unroll
    for (int i = 0; i < 4; i++)
        op[(size_t)(c0 + ty + i * 8) * R + (r0 + tx)] = f2b(tile[tx][ty + i * 8]);
}

// ---------- LayerNorm over C=384, one wave per output row; chunked ----------
__global__ __launch_bounds__(256) void ln_k(const bf16* __restrict__ in,
                                            const float* __restrict__ g,
                                            const float* __restrict__ b,
                                            bf16* __restrict__ out,
                                            int row0, int gather)
{
    int wave = threadIdx.x >> 6, lane = threadIdx.x & 63;
    int row = row0 + blockIdx.x * 4 + wave;
    int src = gather ? wrow_to_token(row) : row;
    const bf16* ip = in + (size_t)src * CD;
    float vals[6];
    float s = 0.f, s2 = 0.f;
#pragma unroll
    for (int i = 0; i < 6; i++) {
        float v = b2f(ip[lane + i * 64]);
        vals[i] = v; s += v; s2 += v * v;
    }
#pragma unroll
    for (int off = 32; off >= 1; off >>= 1) {
        s  += __shfl_xor(s, off);
        s2 += __shfl_xor(s2, off);
    }
    float mean = s * (1.f / CD);
    float var = s2 * (1.f / CD) - mean * mean;
    float rstd = rsqrtf(var + 1e-5f);
    bf16* op = out + (size_t)(row - row0) * CD;
#pragma unroll
    for (int i = 0; i < 6; i++) {
        int c = lane + i * 64;
        op[c] = f2b((vals[i] - mean) * rstd * g[c] + b[c]);
    }
}

// ---------- GEMM: C[M,N] = A[M,K] @ Bt[N,K]^T (+fp32 bias per col), bf16 in, fp32 acc ----------
// m97 structure: 128x128 tile, BK=32, SINGLE-buffer linear LDS, global_load_lds width-16
// staging, __syncthreads drain (proven best of r3/r4/r5 variants on these shapes).
// 1-D grid + bijective chunked XCD swizzle (m204).
// If g1 != nullptr: fused resid1 epilogue -> writes x1[token] = xt[token] + g1*(acc+bias),
// with token = wrow_to_token(row0 + global_row); Cm is then the x1 base (token-major).
__global__ __launch_bounds__(256) void gemm_bt(const bf16* __restrict__ A,
                                               const bf16* __restrict__ Bt,
                                               const float* __restrict__ bias,
                                               bf16* __restrict__ Cm,
                                               int M, int N, int K, int gx,
                                               const bf16* __restrict__ xt,
                                               const float* __restrict__ g1,
                                               int row0)
{
    __shared__ __align__(16) bf16 As[128][32];
    __shared__ __align__(16) bf16 Bs[128][32];
    const int nwg = gridDim.x;
    const int q = nwg >> 3, r = nwg & 7;
    const int xcd = blockIdx.x & 7, id8 = blockIdx.x >> 3;
    const int wgid = (xcd < r ? xcd * (q + 1) : r * (q + 1) + (xcd - r) * q) + id8;
    const int m0 = (wgid / gx) * 128, n0 = (wgid % gx) * 128;

    const int tid = threadIdx.x;
    const int lane = tid & 63, wave = tid >> 6;
    const int rb = (wave >> 1) * 64, cb = (wave & 1) * 64;
    const int lr = lane & 15, ko = (lane >> 4) * 8;
    const int r0s = wave * 32;           // this wave's 32-row staging slab
    const int srow = lane >> 2;          // 0..15 (row within 16-row half-slab)
    const int scol = (lane & 3) * 8;     // element offset (0,8,16,24)

    v4f acc[4][4];
#pragma unroll
    for (int i = 0; i < 4; i++)
#pragma unroll
        for (int j = 0; j < 4; j++) acc[i][j] = (v4f)0.f;

    for (int kk = 0; kk < K; kk += 32) {
#pragma unroll
        for (int h = 0; h < 2; h++) {
            int row = r0s + h * 16 + srow;
            gload_lds16(&A [(size_t)(m0 + row) * K + kk + scol], &As[r0s + h * 16][0]);
            gload_lds16(&Bt[(size_t)(n0 + row) * K + kk + scol], &Bs[r0s + h * 16][0]);
        }
        __syncthreads();
        short8 af[4], bfr[4];
#pragma unroll
        for (int mi = 0; mi < 4; mi++) af[mi]  = *(const short8*)&As[rb + mi * 16 + lr][ko];
#pragma unroll
        for (int ni = 0; ni < 4; ni++) bfr[ni] = *(const short8*)&Bs[cb + ni * 16 + lr][ko];
#pragma unroll
        for (int mi = 0; mi < 4; mi++)
#pragma unroll
            for (int ni = 0; ni < 4; ni++)
                acc[mi][ni] = __builtin_amdgcn_mfma_f32_16x16x32_bf16(af[mi], bfr[ni], acc[mi][ni], 0, 0, 0);
        __syncthreads();
    }

#pragma unroll
    for (int ni = 0; ni < 4; ni++) {
        int col = n0 + cb + ni * 16 + lr;
        float bv = bias ? bias[col] : 0.f;
#pragma unroll
        for (int mi = 0; mi < 4; mi++) {
            int rowb = m0 + rb + mi * 16 + (lane >> 4) * 4;
            if (g1 == nullptr) {
#pragma unroll
                for (int r2 = 0; r2 < 4; r2++)
                    Cm[(size_t)(rowb + r2) * N + col] = f2b(acc[mi][ni][r2] + bv);
            } else {
                float gv = g1[col];
#pragma unroll
                for (int r2 = 0; r2 < 4; r2++) {
                    int token = wrow_to_token(row0 + rowb + r2);
                    size_t xi = (size_t)token * CD + col;
                    Cm[xi] = f2b(b2f(xt[xi]) + gv * (acc[mi][ni][r2] + bv));
                }
            }
        }
    }
}

// ---------- MFMA attention: one wave per (window, head); n=64, hd=48 ----------
// Q/K fragments read DIRECT from global (window qkv is L2/L3-resident; zero LDS reuse).
// LDS: P[64] rows x 128B XOR-swizzled (8KB) + V[64][48] (6KB) = 14336B.
__global__ __launch_bounds__(64) void attn_mfma_k(const bf16* __restrict__ qkv,
                                                  bf16* __restrict__ o)
{
    __shared__ __align__(16) char lds[14336];
    char* Ps = lds;                    // stride 128 B, swizzled
    bf16* Vs = (bf16*)(lds + 8192);    // stride 48 elems (96 B)

    const int lane = threadIdx.x;
    const int lr = lane & 15, grp = lane >> 4;
    const int lw = blockIdx.x >> 3, head = blockIdx.x & 7;

    const bf16* base = qkv + (size_t)lw * 64 * 1152 + head * 48;

    // ---- stage V only ----
#pragma unroll
    for (int it = 0; it < 6; it++) {
        int i = it * 64 + lane;
        int t = i / 6, s = i - t * 6;
        *(uint4*)((char*)Vs + t * 96 + s * 16) =
            *(const uint4*)(base + (size_t)t * 1152 + 768 + s * 8);
    }

    // ---- S = Q K^T : 4x4 tiles of 16x16; fragments direct from global ----
    v4f accs[4][4];
#pragma unroll
    for (int mi = 0; mi < 4; mi++)
#pragma unroll
        for (int ni = 0; ni < 4; ni++) accs[mi][ni] = (v4f)0.f;

    const short8 z8 = (short8)0;
    {
        short8 qf[4], kf[4];
        // k-step 0: k = grp*8 (0..31)
#pragma unroll
        for (int mi = 0; mi < 4; mi++)
            qf[mi] = *(const short8*)(base + (size_t)(mi * 16 + lr) * 1152 + grp * 8);
#pragma unroll
        for (int ni = 0; ni < 4; ni++)
            kf[ni] = *(const short8*)(base + 384 + (size_t)(ni * 16 + lr) * 1152 + grp * 8);
#pragma unroll
        for (int mi = 0; mi < 4; mi++)
#pragma unroll
            for (int ni = 0; ni < 4; ni++)
                accs[mi][ni] = __builtin_amdgcn_mfma_f32_16x16x32_bf16(qf[mi], kf[ni], accs[mi][ni], 0, 0, 0);
        // k-step 1: k = 32 + grp*8; grp>=2 would be k>=48 -> zero fragment (no pad in global)
#pragma unroll
        for (int mi = 0; mi < 4; mi++)
            qf[mi] = (grp < 2) ? *(const short8*)(base + (size_t)(mi * 16 + lr) * 1152 + 32 + grp * 8) : z8;
#pragma unroll
        for (int ni = 0; ni < 4; ni++)
            kf[ni] = (grp < 2) ? *(const short8*)(base + 384 + (size_t)(ni * 16 + lr) * 1152 + 32 + grp * 8) : z8;
#pragma unroll
        for (int mi = 0; mi < 4; mi++)
#pragma unroll
            for (int ni = 0; ni < 4; ni++)
                accs[mi][ni] = __builtin_amdgcn_mfma_f32_16x16x32_bf16(qf[mi], kf[ni], accs[mi][ni], 0, 0, 0);
    }

    // ---- wave-parallel softmax over cols ----
    const float scale = 0.14433756729740643f; // 48^-0.5
#pragma unroll
    for (int mi = 0; mi < 4; mi++)
#pragma unroll
        for (int ni = 0; ni < 4; ni++) accs[mi][ni] *= scale;

    float inv_s[4][4];
#pragma unroll
    for (int mi = 0; mi < 4; mi++) {
#pragma unroll
        for (int r = 0; r < 4; r++) {
            float mx = fmaxf(fmaxf(accs[mi][0][r], accs[mi][1][r]),
                             fmaxf(accs[mi][2][r], accs[mi][3][r]));
#pragma unroll
            for (int off = 8; off >= 1; off >>= 1) mx = fmaxf(mx, __shfl_xor(mx, off));
            float sum = 0.f;
#pragma unroll
            for (int ni = 0; ni < 4; ni++) {
                float e = __expf(accs[mi][ni][r] - mx);
                accs[mi][ni][r] = e;
                sum += e;
            }
#pragma unroll
            for (int off = 8; off >= 1; off >>= 1) sum += __shfl_xor(sum, off);
            inv_s[mi][r] = 1.f / sum;
        }
    }

    // ---- write unnormalized P (bf16) to swizzled LDS ----
#pragma unroll
    for (int mi = 0; mi < 4; mi++)
#pragma unroll
        for (int ni = 0; ni < 4; ni++)
#pragma unroll
            for (int r = 0; r < 4; r++) {
                int i = mi * 16 + grp * 4 + r;
                int j = ni * 16 + lr;
                int byte = (i * 128 + j * 2) ^ ((i & 7) << 4);
                *(bf16*)(Ps + byte) = f2b(accs[mi][ni][r]);
            }

    // ---- O = P V : M=64, N=48, K=64 -> 4x3 tiles, 2 k-steps ----
    v4f acco[4][3];
#pragma unroll
    for (int mi = 0; mi < 4; mi++)
#pragma unroll
        for (int ni = 0; ni < 3; ni++) acco[mi][ni] = (v4f)0.f;

    const short* vsp = (const short*)Vs;
#pragma unroll
    for (int kk = 0; kk < 2; kk++) {
        int k0 = kk * 32 + grp * 8;
        short8 pf[4];
#pragma unroll
        for (int mi = 0; mi < 4; mi++) {
            int row = mi * 16 + lr;
            int byte = (row * 128 + k0 * 2) ^ ((row & 7) << 4);
            pf[mi] = *(const short8*)(Ps + byte);
        }
        short8 vf[3];
#pragma unroll
        for (int ni = 0; ni < 3; ni++) {
#pragma unroll
            for (int jj = 0; jj < 8; jj++)
                vf[ni][jj] = vsp[(k0 + jj) * 48 + ni * 16 + lr];
        }
#pragma unroll
        for (int mi = 0; mi < 4; mi++)
#pragma unroll
            for (int ni = 0; ni < 3; ni++)
                acco[mi][ni] = __builtin_amdgcn_mfma_f32_16x16x32_bf16(pf[mi], vf[ni], acco[mi][ni], 0, 0, 0);
    }

    // ---- epilogue: scale by 1/rowsum, store ----
    bf16* op = o + (size_t)lw * 64 * CD + head * 48;
#pragma unroll
    for (int mi = 0; mi < 4; mi++)
#pragma unroll
        for (int r = 0; r < 4; r++) {
            int t = mi * 16 + grp * 4 + r;
            float is = inv_s[mi][r];
#pragma unroll
            for (int ni = 0; ni < 3; ni++)
                op[(size_t)t * CD + ni * 16 + lr] = f2b(acco[mi][ni][r] * is);
        }
}

// ---------- depthwise 3x3 conv + bias + exact GELU: register sliding window ----------
__global__ __launch_bounds__(256) void dwconv_gelu_k(const bf16* __restrict__ m1c,
                                                     const float* __restrict__ wgt,
                                                     const float* __restrict__ bias,
                                                     bf16* __restrict__ gc)
{
    const int c  = blockIdx.x * 64 + (threadIdx.x & 63);
    const int xq = threadIdx.x >> 6;
    const int xx = blockIdx.y * 8 + xq * 2;     // first of 2 x positions (<= 54)
    const int lb = blockIdx.z >> 2;
    const int ys = (blockIdx.z & 3) * 14;

    float w9[9];
#pragma unroll
    for (int i = 0; i < 9; i++) w9[i] = wgt[c * 9 + i];
    const float bs = bias[c];

    const bf16* base = m1c + (size_t)lb * ND * HID + c;
    bool  v[4];
    const bf16* colp[4];
#pragma unroll
    for (int i = 0; i < 4; i++) {
        int xc = xx - 1 + i;
        v[i] = (xc >= 0 && xc < HH);
        int xcl = xc < 0 ? 0 : (xc > HH - 1 ? HH - 1 : xc);
        colp[i] = base + (size_t)xcl * HID;
    }
    const size_t ystride = (size_t)HH * HID;

    float win[3][4];
    {
        int ym = ys - 1;
        int ymc = ym < 0 ? 0 : ym;
        bool yv = (ym >= 0);
#pragma unroll
        for (int i = 0; i < 4; i++)
            win[0][i] = (yv && v[i]) ? b2f(colp[i][(size_t)ymc * ystride]) : 0.f;
#pragma unroll
        for (int i = 0; i < 4; i++)
            win[1][i] = v[i] ? b2f(colp[i][(size_t)ys * ystride]) : 0.f;
    }

#pragma unroll
    for (int s = 0; s < 14; s++) {
        const int y = ys + s;
        const int yp = y + 1;
        const bool yv = (yp < HH);
        const int ypc = yv ? yp : (HH - 1);
#pragma unroll
        for (int i = 0; i < 4; i++)
            win[2][i] = (yv && v[i]) ? b2f(colp[i][(size_t)ypc * ystride]) : 0.f;

        float a0 = bs, a1 = bs;
#pragma unroll
        for (int r = 0; r < 3; r++)
#pragma unroll
            for (int j = 0; j < 3; j++) {
                a0 = fmaf(w9[r * 3 + j], win[r][j],     a0);
                a1 = fmaf(w9[r * 3 + j], win[r][j + 1], a1);
            }
        float g0 = 0.5f * a0 * (1.f + erff(a0 * 0.70710678118654752f));
        float g1 = 0.5f * a1 * (1.f + erff(a1 * 0.70710678118654752f));
        size_t o0 = ((size_t)lb * ND + (size_t)y * HH + xx) * HID + c;
        gc[o0]       = f2b(g0);
        gc[o0 + HID] = f2b(g1);

#pragma unroll
        for (int i = 0; i < 4; i++) { win[0][i] = win[1][i]; win[1][i] = win[2][i]; }
    }
}

// ---------- residual 2 + transpose to NCHW fp32 output (chunk of nb images at b0) ----------
__global__ __launch_bounds__(256) void resid2_k(const bf16* __restrict__ x1,
                                                const bf16* __restrict__ m2c,
                                                const float* __restrict__ gamma2,
                                                float* __restrict__ out, int b0)
{
    __shared__ float tile[32][33];
    int n0 = blockIdx.x * 32, c0 = blockIdx.y * 32;
    int lb = blockIdx.z, gb = b0 + lb;
    int tx = threadIdx.x & 31, ty = threadIdx.x >> 5;
#pragma unroll
    for (int i = 0; i < 4; i++) {
        int n = n0 + ty + i * 8, c = c0 + tx;
        size_t sx1 = ((size_t)gb * ND + n) * CD + c;
        size_t sm  = ((size_t)lb * ND + n) * CD + c;
        tile[ty + i * 8][tx] = b2f(x1[sx1]) + gamma2[c] * b2f(m2c[sm]);
    }
    __syncthreads();
#pragma unroll
    for (int i = 0; i < 4; i++) {
        int c = c0 + ty + i * 8, n = n0 + tx;
        out[((size_t)gb * CD + c) * ND + n] = tile[tx][ty + i * 8];
    }
}

extern "C" void kernel_launch(void* const* d_in, const int* in_sizes, int n_in,
                              void* d_out, int out_size, void* d_ws, size_t ws_size,
                              hipStream_t stream) {
    const float* x      = (const float*)d_in[0];
    const float* ln1_g  = (const float*)d_in[1];
    const float* ln1_b  = (const float*)d_in[2];
    const float* qkv_w  = (const float*)d_in[3];
    const float* proj_w = (const float*)d_in[4];
    const float* proj_b = (const float*)d_in[5];
    const float* ln2_g  = (const float*)d_in[6];
    const float* ln2_b  = (const float*)d_in[7];
    const float* fc1_w  = (const float*)d_in[8];
    const float* fc1_b  = (const float*)d_in[9];
    const float* dw_w   = (const float*)d_in[10];
    const float* dw_b   = (const float*)d_in[11];
    const float* fc2_w  = (const float*)d_in[12];
    const float* fc2_b  = (const float*)d_in[13];
    const float* gamma1 = (const float*)d_in[14];
    const float* gamma2 = (const float*)d_in[15];
    float* out = (float*)d_out;

    const size_t SZ_TOK = (size_t)MROWS * CD * 2;   // bf16 token-major
    const size_t S0 = 2 * SZ_TOK;
    const size_t WTS = 3538944;                     // transposed-weights block

    // minimal attention-phase footprint (ca=8) used as floor when sizing MLP chunks
    const size_t attn_end8 = S0 + (size_t)(MROWS / 8) * CD * 2 + (size_t)(MROWS / 8) * 1152 * 2;

    // MLP chunking: smallest cm in {2,4,8,16} that fits (bigger chunk -> bigger grids,
    // esp. fc2 which has only 3 column-tiles)
    int cm = 16;
    for (int cand = 2; cand < 16; cand <<= 1) {
        size_t mc2 = (size_t)(BB / cand) * ND;
        size_t me = S0 + mc2 * CD * 2 + 2 * mc2 * HID * 2;
        size_t tot = (me > attn_end8 ? me : attn_end8) + WTS;
        if (ws_size >= tot) { cm = cand; break; }
    }
    const int nb = BB / cm;
    const int Mc2 = nb * ND;
    const size_t sz_h2 = (size_t)Mc2 * CD * 2;
    const size_t sz_m1 = (size_t)Mc2 * HID * 2;
    const size_t mlp_end = S0 + sz_h2 + 2 * sz_m1;

    // attention chunking: smallest ca in {2,4,8} that fits
    int ca = 0;
    size_t sz_h = 0, attn_end = 0;
    for (int cand = 2; cand <= 8 && !ca; cand <<= 1) {
        int McA_ = MROWS / cand;
        size_t h_ = (size_t)McA_ * CD * 2, qk_ = (size_t)McA_ * 1152 * 2;
        size_t ae = S0 + h_ + qk_;
        size_t tot = (mlp_end > ae ? mlp_end : ae) + WTS;
        if (ws_size >= tot) { ca = cand; sz_h = h_; attn_end = ae; }
    }
    if (!ca) return;
    const int McA = MROWS / ca;

    const size_t Wo = (mlp_end > attn_end ? mlp_end : attn_end);

    char* w = (char*)d_ws;
    bf16* xt      = (bf16*)(w + 0);
    bf16* x1      = (bf16*)(w + SZ_TOK);
    bf16* hc      = (bf16*)(w + S0);                // attention: h / o (aliased)
    bf16* qkvc    = (bf16*)(w + S0 + sz_h);         // attention: qkv (aliased)
    bf16* h2c     = (bf16*)(w + S0);                // MLP: h2 / m2 (aliased)
    bf16* m1c     = (bf16*)(w + S0 + sz_h2);
    bf16* gc      = (bf16*)(w + S0 + sz_h2 + sz_m1);
    bf16* qkv_wt  = (bf16*)(w + Wo);
    bf16* proj_wt = (bf16*)(w + Wo + 884736);
    bf16* fc1_wt  = (bf16*)(w + Wo + 884736 + 294912);
    bf16* fc2_wt  = (bf16*)(w + Wo + 884736 + 294912 + 1179648);

    dim3 blk(256);

    // fp32 -> bf16 transposes: x -> xt (token-major), weights -> K-contiguous (B^T)
    transpose_f2b_k<<<dim3(98, 12, 32), blk, 0, stream>>>(x, xt, CD, ND);
    transpose_f2b_k<<<dim3(36, 12, 1), blk, 0, stream>>>(qkv_w, qkv_wt, CD, 1152);
    transpose_f2b_k<<<dim3(12, 12, 1), blk, 0, stream>>>(proj_w, proj_wt, CD, CD);
    transpose_f2b_k<<<dim3(48, 12, 1), blk, 0, stream>>>(fc1_w, fc1_wt, CD, HID);
    transpose_f2b_k<<<dim3(12, 48, 1), blk, 0, stream>>>(fc2_w, fc2_wt, HID, CD);

    // ---- attention phase: ca chunks of McA window rows ----
    for (int ch = 0; ch < ca; ch++) {
        int row0 = ch * McA;
        ln_k<<<McA / 4, blk, 0, stream>>>(xt, ln1_g, ln1_b, hc, row0, 1);
        gemm_bt<<<dim3(9 * (McA / 128)), blk, 0, stream>>>(hc, qkv_wt, nullptr, qkvc,
                                                           McA, 1152, CD, 9, nullptr, nullptr, 0);
        attn_mfma_k<<<(McA / 64) * 8, dim3(64), 0, stream>>>(qkvc, hc);   // o -> hc
        // proj GEMM with fused resid1: writes x1[token] = xt[token] + gamma1*(o@W + b)
        gemm_bt<<<dim3(3 * (McA / 128)), blk, 0, stream>>>(hc, proj_wt, proj_b, x1,
                                                           McA, CD, CD, 3, xt, gamma1, row0);
    }

    // ---- MLP phase: cm chunks of nb whole images ----
    for (int ch = 0; ch < cm; ch++) {
        int r0 = ch * Mc2, b0 = ch * nb;
        ln_k<<<Mc2 / 4, blk, 0, stream>>>(x1, ln2_g, ln2_b, h2c, r0, 0);
        gemm_bt<<<dim3(12 * (Mc2 / 128)), blk, 0, stream>>>(h2c, fc1_wt, fc1_b, m1c,
                                                            Mc2, HID, CD, 12, nullptr, nullptr, 0);
        dwconv_gelu_k<<<dim3(HID / 64, 7, nb * 4), blk, 0, stream>>>(m1c, dw_w, dw_b, gc);
        gemm_bt<<<dim3(3 * (Mc2 / 128)), blk, 0, stream>>>(gc, fc2_wt, fc2_b, h2c,
                                                           Mc2, CD, HID, 3, nullptr, nullptr, 0);
        resid2_k<<<dim3(98, 12, nb), blk, 0, stream>>>(x1, h2c, gamma2, out, b0);
    }
}